// Round 9
// baseline (519.478 us; speedup 1.0000x reference)
//
#include <hip/hip_runtime.h>
#include <math.h>

// GAT 3-layer. Round 9:
//  - agg: lane-specialized exp (1 per edge-head, bpermute broadcast), denom out
//    of inner loop (shfl_xor reduce). Inner loop: 2 bpermute + gather + 2 FMA.
//  - CSR: fixed-capacity buckets (BCAP) -> no count/scan/memset; rowbe int2.

#define HEADS 4
#define HID   32
#define NCLS  40
#define BSH   8
#define CH    4096
#define BCAP  6144

typedef __attribute__((ext_vector_type(8))) short bf16x8;
typedef __attribute__((ext_vector_type(4))) float f32x4;

static __device__ __forceinline__ unsigned short f2bf(float f) {
    unsigned int u = __float_as_uint(f);
    u += 0x7fffu + ((u >> 16) & 1u);   // RNE
    return (unsigned short)(u >> 16);
}
static __device__ __forceinline__ float bflo(unsigned int v) {
    return __uint_as_float(v << 16);
}
static __device__ __forceinline__ float bfhi(unsigned int v) {
    return __uint_as_float(v & 0xffff0000u);
}
static __device__ __forceinline__ unsigned int pack2bf(float lo, float hi) {
    return (unsigned int)f2bf(lo) | ((unsigned int)f2bf(hi) << 16);
}

// ---------------- bucketed CSR build (fixed-capacity buckets) ----------------

__global__ __launch_bounds__(256) void bucket_init(int NBUCK, int* __restrict__ bcur) {
    int b = blockIdx.x * 256 + threadIdx.x;
    if (b < NBUCK) bcur[b] = b * BCAP;
}

__global__ __launch_bounds__(256) void bucket_partition(const int* __restrict__ src,
                                                        const int* __restrict__ dst, int E,
                                                        int NBUCK, int* __restrict__ bcur,
                                                        unsigned long long* __restrict__ ebuf) {
    __shared__ int h[512];
    __shared__ int base[512];
    int tid = threadIdx.x;
    int e0 = blockIdx.x * CH;
    for (int i = tid; i < NBUCK; i += 256) h[i] = 0;
    __syncthreads();
    #pragma unroll
    for (int l = 0; l < CH / 256; ++l) {
        int g = e0 + l * 256 + tid;
        if (g < E) atomicAdd(&h[dst[g] >> BSH], 1);
    }
    __syncthreads();
    for (int i = tid; i < NBUCK; i += 256) {
        int c = h[i];
        if (c) base[i] = atomicAdd(&bcur[i], c);
    }
    __syncthreads();
    #pragma unroll
    for (int l = 0; l < CH / 256; ++l) {
        int g = e0 + l * 256 + tid;
        if (g < E) {
            int d = dst[g];
            int p = atomicAdd(&base[d >> BSH], 1);
            ebuf[p] = ((unsigned long long)(unsigned)d << 32) | (unsigned)src[g];
        }
    }
}

__global__ __launch_bounds__(256) void bucket_csr(const unsigned long long* __restrict__ ebuf,
                                                  const int* __restrict__ bcur, int N,
                                                  int2* __restrict__ rowbe,
                                                  int* __restrict__ csrc) {
    __shared__ int cnt[256];
    __shared__ int s[256];
    int b = blockIdx.x, tid = threadIdx.x;
    int beg = b * BCAP, end = bcur[b];
    int d0 = b << BSH;
    cnt[tid] = 0;
    __syncthreads();
    for (int i = beg + tid; i < end; i += 256)
        atomicAdd(&cnt[(int)(ebuf[i] >> 32) - d0], 1);
    __syncthreads();
    int v = cnt[tid];
    s[tid] = v;
    __syncthreads();
    for (int off = 1; off < 256; off <<= 1) {
        int t = (tid >= off) ? s[tid - off] : 0;
        __syncthreads();
        s[tid] += t;
        __syncthreads();
    }
    int excl = s[tid] - v;
    int d = d0 + tid;
    if (d < N) rowbe[d] = make_int2(beg + excl, beg + excl + v);
    cnt[tid] = beg + excl;
    __syncthreads();
    for (int i = beg + tid; i < end; i += 256) {
        unsigned long long e = ebuf[i];
        int p = atomicAdd(&cnt[(int)(e >> 32) - d0], 1);
        csrc[p] = (int)(e & 0xffffffffu);
    }
}

// ---------------- weight prep: Wt[m][k] = bf16(W[k][m]) ----------------

__global__ __launch_bounds__(256) void prep_wt(const float* __restrict__ W,
                                               unsigned short* __restrict__ Wt,
                                               int K, int M) {
    int g = blockIdx.x * 256 + threadIdx.x;
    if (g < K * M) {
        int m = g / K, k = g % K;
        Wt[g] = f2bf(W[(size_t)k * M + m]);
    }
}

// ---------------- MFMA GEMM ----------------

template <bool AFP32, bool OBF, bool WIDEN>
__global__ __launch_bounds__(256) void gemm_mfma(const void* __restrict__ Asrc,
                                                 const unsigned short* __restrict__ Wt,
                                                 void* __restrict__ Y,
                                                 int N, int K, int M) {
    constexpr int WRF = WIDEN ? 4 : 2;
    constexpr int WCF = WIDEN ? 4 : 3;
    __shared__ __align__(16) unsigned short As[128][40];
    __shared__ __align__(16) unsigned short Bs[128][40];
    const int t = threadIdx.x;
    const int lane = t & 63, w = t >> 6;
    const int r0 = blockIdx.x * 128;
    const int wrow = WIDEN ? (w >> 1) * 64 : w * 32;
    const int wcol = WIDEN ? (w & 1) * 64 : 0;
    const int srow = t >> 1, shalf = t & 1;
    const int lr = lane & 15, lq = lane >> 4;
    f32x4 acc[WRF][WCF];
    #pragma unroll
    for (int f = 0; f < WRF; ++f)
        #pragma unroll
        for (int g = 0; g < WCF; ++g)
            acc[f][g] = (f32x4){0.f, 0.f, 0.f, 0.f};

    for (int k0 = 0; k0 < K; k0 += 32) {
        {
            int gr = r0 + srow;
            if (gr < N) {
                if constexpr (AFP32) {
                    const float* gp = (const float*)Asrc + (size_t)gr * K + k0 + shalf * 16;
                    float4 f0 = *(const float4*)(gp + 0);
                    float4 f1 = *(const float4*)(gp + 4);
                    float4 f2 = *(const float4*)(gp + 8);
                    float4 f3 = *(const float4*)(gp + 12);
                    *(uint4*)&As[srow][shalf * 16 + 0] =
                        make_uint4(pack2bf(f0.x, f0.y), pack2bf(f0.z, f0.w),
                                   pack2bf(f1.x, f1.y), pack2bf(f1.z, f1.w));
                    *(uint4*)&As[srow][shalf * 16 + 8] =
                        make_uint4(pack2bf(f2.x, f2.y), pack2bf(f2.z, f2.w),
                                   pack2bf(f3.x, f3.y), pack2bf(f3.z, f3.w));
                } else {
                    const uint4* gp = (const uint4*)((const unsigned short*)Asrc +
                                                     (size_t)gr * K + k0 + shalf * 16);
                    *(uint4*)&As[srow][shalf * 16 + 0] = gp[0];
                    *(uint4*)&As[srow][shalf * 16 + 8] = gp[1];
                }
            }
        }
        {
            int col = srow;
            if (col < M) {
                const uint4* gp = (const uint4*)(Wt + (size_t)col * K + k0 + shalf * 16);
                *(uint4*)&Bs[col][shalf * 16 + 0] = gp[0];
                *(uint4*)&Bs[col][shalf * 16 + 8] = gp[1];
            }
        }
        __syncthreads();
        bf16x8 af[WRF], bfr[WCF];
        #pragma unroll
        for (int f = 0; f < WRF; ++f)
            af[f] = *(const bf16x8*)&As[wrow + f * 16 + lr][lq * 8];
        #pragma unroll
        for (int g = 0; g < WCF; ++g)
            bfr[g] = *(const bf16x8*)&Bs[wcol + g * 16 + lr][lq * 8];
        #pragma unroll
        for (int f = 0; f < WRF; ++f)
            #pragma unroll
            for (int g = 0; g < WCF; ++g)
                acc[f][g] = __builtin_amdgcn_mfma_f32_16x16x32_bf16(af[f], bfr[g],
                                                                   acc[f][g], 0, 0, 0);
        __syncthreads();
    }
    #pragma unroll
    for (int f = 0; f < WRF; ++f) {
        #pragma unroll
        for (int g = 0; g < WCF; ++g) {
            int col = wcol + g * 16 + lr;
            if (!WIDEN && col >= M) continue;
            #pragma unroll
            for (int r = 0; r < 4; ++r) {
                int row = r0 + wrow + f * 16 + lq * 4 + r;
                if (row < N) {
                    if constexpr (OBF)
                        ((unsigned short*)Y)[(size_t)row * M + col] = f2bf(acc[f][g][r]);
                    else
                        ((float*)Y)[(size_t)row * M + col] = acc[f][g][r];
                }
            }
        }
    }
}

// ---------------- el / er ----------------

template <int H, int D, bool BF>
__global__ __launch_bounds__(256) void elr_kernel(const void* __restrict__ hv,
                                                  const float* __restrict__ al,
                                                  const float* __restrict__ ar,
                                                  float* __restrict__ el,
                                                  float* __restrict__ er, int N) {
    int g = blockIdx.x * blockDim.x + threadIdx.x;
    int n = g / H, hh = g % H;
    if (n >= N) return;
    float sl = 0.f, sr = 0.f;
    if constexpr (BF) {
        const unsigned short* hp = (const unsigned short*)hv + (size_t)n * H * D + hh * D;
        #pragma unroll
        for (int d = 0; d < D; d += 8) {
            uint4 u = *(const uint4*)(hp + d);
            float4 a0 = *(const float4*)(al + hh * D + d);
            float4 a1 = *(const float4*)(al + hh * D + d + 4);
            float4 r0 = *(const float4*)(ar + hh * D + d);
            float4 r1 = *(const float4*)(ar + hh * D + d + 4);
            float h0 = bflo(u.x), h1 = bfhi(u.x);
            float h2 = bflo(u.y), h3 = bfhi(u.y);
            float h4 = bflo(u.z), h5 = bfhi(u.z);
            float h6 = bflo(u.w), h7 = bfhi(u.w);
            sl += h0 * a0.x + h1 * a0.y + h2 * a0.z + h3 * a0.w
                + h4 * a1.x + h5 * a1.y + h6 * a1.z + h7 * a1.w;
            sr += h0 * r0.x + h1 * r0.y + h2 * r0.z + h3 * r0.w
                + h4 * r1.x + h5 * r1.y + h6 * r1.z + h7 * r1.w;
        }
    } else {
        const float* hp = (const float*)hv + (size_t)n * H * D + hh * D;
        #pragma unroll
        for (int d = 0; d < D; d += 4) {
            float4 hvv = *(const float4*)(hp + d);
            float4 av = *(const float4*)(al + hh * D + d);
            float4 rv = *(const float4*)(ar + hh * D + d);
            sl += hvv.x * av.x + hvv.y * av.y + hvv.z * av.z + hvv.w * av.w;
            sr += hvv.x * rv.x + hvv.y * rv.y + hvv.z * rv.z + hvv.w * rv.w;
        }
    }
    el[(size_t)n * H + hh] = sl;
    er[(size_t)n * H + hh] = sr;
}

// ---------------- aggregation: wave/dst, lane-specialized exp ----------------
// Chunk of 16 edges: lane (g=lane>>4, j=lane&15) computes ex for edge j, head g
// once; inner loop broadcasts via bpermute. Denominator: local partial +
// shfl_xor reduce within the 16-lane head group after the edge loop.

template <int H, int D, bool ELU, bool BFW, bool OB>
__global__ __launch_bounds__(256) void agg_kernel(const void* __restrict__ hsrcv,
                                                  const float* __restrict__ el,
                                                  const float* __restrict__ er,
                                                  const float* __restrict__ bias,
                                                  const int2* __restrict__ rowbe,
                                                  const int* __restrict__ csrc,
                                                  void* __restrict__ outv, int N) {
    constexpr int HD = H * D;
    int wid = (int)(((size_t)blockIdx.x * blockDim.x + threadIdx.x) >> 6);
    int lane = threadIdx.x & 63;
    if (wid >= N) return;
    const int j16 = lane & 15;
    const int base16 = lane & 48;
    const int myhead = BFW ? (lane >> 4) : 0;   // for BFW: exp-head == channel-head
    int eb = BFW ? lane * 2 : lane;
    bool active = BFW || (lane < HD);
    float er_m = er[(size_t)wid * H + myhead];
    int2 be = rowbe[wid];
    int beg = be.x, end = be.y;
    const unsigned int* hb = (const unsigned int*)hsrcv;
    const float* hf = (const float*)hsrcv;

    float dpart = 0.f, a0 = 0.f, a1 = 0.f;

    for (int chunk = beg; chunk < end; chunk += 16) {
        int cnt16 = min(16, end - chunk);
        int sm = (j16 < cnt16) ? csrc[chunk + j16] : 0;
        float ex_r = 0.f;
        if (j16 < cnt16) {
            float e = el[(size_t)sm * H + myhead] + er_m;
            e = (e > 0.f) ? e : 0.2f * e;
            ex_r = __expf(e);
        }
        dpart += ex_r;
        #pragma unroll
        for (int j = 0; j < 16; ++j) {
            if (j >= cnt16) break;
            float ex = __shfl(ex_r, base16 + j);
            int s = __shfl(sm, base16 + j);
            if (BFW) {
                unsigned int v = hb[(size_t)s * (HD / 2) + lane];
                a0 = fmaf(ex, bflo(v), a0);
                a1 = fmaf(ex, bfhi(v), a1);
            } else {
                float hx = active ? hf[(size_t)s * HD + eb] : 0.f;
                a0 = fmaf(ex, hx, a0);
            }
        }
    }

    // denominator: reduce partials within the 16-lane head group
    float denom = dpart;
    denom += __shfl_xor(denom, 1);
    denom += __shfl_xor(denom, 2);
    denom += __shfl_xor(denom, 4);
    denom += __shfl_xor(denom, 8);

    float inv = 1.f / (denom + 1e-9f);
    if (BFW) {
        float o0 = a0 * inv + bias[eb];
        float o1 = a1 * inv + bias[eb + 1];
        if (ELU) {
            o0 = (o0 > 0.f) ? o0 : expm1f(o0);
            o1 = (o1 > 0.f) ? o1 : expm1f(o1);
        }
        if constexpr (OB) {
            ((unsigned int*)outv)[(size_t)wid * (HD / 2) + lane] = pack2bf(o0, o1);
        } else {
            *(float2*)((float*)outv + (size_t)wid * HD + eb) = make_float2(o0, o1);
        }
    } else if (active) {
        float o = a0 * inv + bias[eb];
        if (ELU) o = (o > 0.f) ? o : expm1f(o);
        ((float*)outv)[(size_t)wid * HD + eb] = o;
    }
}

// ---------------- launch ----------------

extern "C" void kernel_launch(void* const* d_in, const int* in_sizes, int n_in,
                              void* d_out, int out_size, void* d_ws, size_t ws_size,
                              hipStream_t stream) {
    const float* x    = (const float*)d_in[0];
    const int* esrc   = (const int*)d_in[1];
    const int* edst   = (const int*)d_in[2];
    const float* W1   = (const float*)d_in[3];
    const float* al1  = (const float*)d_in[4];
    const float* ar1  = (const float*)d_in[5];
    const float* b1   = (const float*)d_in[6];
    const float* W2   = (const float*)d_in[7];
    const float* al2  = (const float*)d_in[8];
    const float* ar2  = (const float*)d_in[9];
    const float* b2   = (const float*)d_in[10];
    const float* W3   = (const float*)d_in[11];
    const float* al3  = (const float*)d_in[12];
    const float* ar3  = (const float*)d_in[13];
    const float* b3   = (const float*)d_in[14];

    const int FIN = 256;
    const int N = in_sizes[0] / FIN;    // 100000
    const int E = in_sizes[1];          // 1600000
    const int D1 = HEADS * HID;         // 128
    const int NBUCK = (N + 255) >> BSH; // 391

    unsigned short* Abf = (unsigned short*)d_ws;              // N*128 bf16
    unsigned short* Cbf = Abf + (size_t)N * D1;               // N*128 bf16
    float* A32 = (float*)(Cbf + (size_t)N * D1);              // N*40 fp32
    float* el  = A32 + (size_t)N * NCLS;                      // N*4
    float* er  = el + (size_t)N * HEADS;                      // N*4
    int2* rowbe = (int2*)(er + (size_t)N * HEADS);            // N int2
    int* csrc   = (int*)(rowbe + N);                          // NBUCK*BCAP
    int* bcur   = csrc + (size_t)NBUCK * BCAP;                // NBUCK
    unsigned short* Wt1 = (unsigned short*)(bcur + NBUCK);    // 128*256
    unsigned short* Wt2 = Wt1 + 128 * 256;                    // 128*128
    unsigned short* Wt3 = Wt2 + 128 * 128;                    // 40*128
    unsigned long long* ebuf = (unsigned long long*)Abf;      // NBUCK*BCAP*8 <= 25.6MB

    int WGRID = (int)(((size_t)N * 64 + 255) / 256);
    int PB = (E + CH - 1) / CH;
    int GB = (N + 127) / 128;

    // ---- weight prep ----
    prep_wt<<<(256 * 128 + 255) / 256, 256, 0, stream>>>(W1, Wt1, FIN, D1);
    prep_wt<<<(128 * 128 + 255) / 256, 256, 0, stream>>>(W2, Wt2, D1, D1);
    prep_wt<<<(128 * 40 + 255) / 256, 256, 0, stream>>>(W3, Wt3, D1, NCLS);

    // ---- CSR build (fixed-capacity buckets) ----
    bucket_init<<<(NBUCK + 255) / 256, 256, 0, stream>>>(NBUCK, bcur);
    bucket_partition<<<PB, 256, 0, stream>>>(esrc, edst, E, NBUCK, bcur, ebuf);
    bucket_csr<<<NBUCK, 256, 0, stream>>>(ebuf, bcur, N, rowbe, csrc);

    // ---- layer 1 ----
    gemm_mfma<true, true, true><<<GB, 256, 0, stream>>>(x, Wt1, Abf, N, FIN, D1);
    elr_kernel<HEADS, HID, true><<<(N * HEADS + 255) / 256, 256, 0, stream>>>(Abf, al1, ar1, el, er, N);
    agg_kernel<HEADS, HID, true, true, true><<<WGRID, 256, 0, stream>>>(Abf, el, er, b1, rowbe, csrc, Cbf, N);

    // ---- layer 2 ----
    gemm_mfma<false, true, true><<<GB, 256, 0, stream>>>(Cbf, Wt2, Abf, N, D1, D1);
    elr_kernel<HEADS, HID, true><<<(N * HEADS + 255) / 256, 256, 0, stream>>>(Abf, al2, ar2, el, er, N);
    agg_kernel<HEADS, HID, true, true, true><<<WGRID, 256, 0, stream>>>(Abf, el, er, b2, rowbe, csrc, Cbf, N);

    // ---- layer 3 ----
    gemm_mfma<false, false, false><<<GB, 256, 0, stream>>>(Cbf, Wt3, A32, N, D1, NCLS);
    elr_kernel<1, NCLS, false><<<(N + 255) / 256, 256, 0, stream>>>(A32, al3, ar3, el, er, N);
    agg_kernel<1, NCLS, false, false, false><<<WGRID, 256, 0, stream>>>(A32, el, er, b3, rowbe, csrc, d_out, N);
}

// Round 10
// 363.062 us; speedup vs baseline: 1.4308x; 1.4308x over previous
//
#include <hip/hip_runtime.h>
#include <math.h>

// GAT 3-layer. Round 10: revert agg to round-8 structure (redundant per-lane
// exp = free parallelism; round-9 bpermute broadcast serialized the loop).
// Keep: fixed-capacity bucket CSR (no count/scan), rowbe int2, fused prep.

#define HEADS 4
#define HID   32
#define NCLS  40
#define BSH   8
#define CH    4096
#define BCAP  6144

typedef __attribute__((ext_vector_type(8))) short bf16x8;
typedef __attribute__((ext_vector_type(4))) float f32x4;

static __device__ __forceinline__ unsigned short f2bf(float f) {
    unsigned int u = __float_as_uint(f);
    u += 0x7fffu + ((u >> 16) & 1u);   // RNE
    return (unsigned short)(u >> 16);
}
static __device__ __forceinline__ float bflo(unsigned int v) {
    return __uint_as_float(v << 16);
}
static __device__ __forceinline__ float bfhi(unsigned int v) {
    return __uint_as_float(v & 0xffff0000u);
}
static __device__ __forceinline__ unsigned int pack2bf(float lo, float hi) {
    return (unsigned int)f2bf(lo) | ((unsigned int)f2bf(hi) << 16);
}

// ---------------- fused prep: Wt1/Wt2/Wt3 transpose+cast, bcur init ----------------

__global__ __launch_bounds__(256) void prep_all(const float* __restrict__ W1,
                                                const float* __restrict__ W2,
                                                const float* __restrict__ W3,
                                                unsigned short* __restrict__ Wt1,
                                                unsigned short* __restrict__ Wt2,
                                                unsigned short* __restrict__ Wt3,
                                                int NBUCK, int* __restrict__ bcur) {
    int g = blockIdx.x * 256 + threadIdx.x;
    if (g < 32768) {                       // Wt1: [128][256]
        int m = g >> 8, k = g & 255;
        Wt1[g] = f2bf(W1[(size_t)k * 128 + m]);
    } else if (g < 49152) {                // Wt2: [128][128]
        int g2 = g - 32768;
        int m = g2 >> 7, k = g2 & 127;
        Wt2[g2] = f2bf(W2[(size_t)k * 128 + m]);
    } else if (g < 54272) {                // Wt3: [40][128]
        int g3 = g - 49152;
        int m = g3 >> 7, k = g3 & 127;
        Wt3[g3] = f2bf(W3[(size_t)k * 40 + m]);
    } else if (g - 54272 < NBUCK) {
        int b = g - 54272;
        bcur[b] = b * BCAP;
    }
}

// ---------------- bucketed CSR build (fixed-capacity buckets) ----------------

__global__ __launch_bounds__(256) void bucket_partition(const int* __restrict__ src,
                                                        const int* __restrict__ dst, int E,
                                                        int NBUCK, int* __restrict__ bcur,
                                                        unsigned long long* __restrict__ ebuf) {
    __shared__ int h[512];
    __shared__ int base[512];
    int tid = threadIdx.x;
    int e0 = blockIdx.x * CH;
    for (int i = tid; i < NBUCK; i += 256) h[i] = 0;
    __syncthreads();
    #pragma unroll
    for (int l = 0; l < CH / 256; ++l) {
        int g = e0 + l * 256 + tid;
        if (g < E) atomicAdd(&h[dst[g] >> BSH], 1);
    }
    __syncthreads();
    for (int i = tid; i < NBUCK; i += 256) {
        int c = h[i];
        if (c) base[i] = atomicAdd(&bcur[i], c);
    }
    __syncthreads();
    #pragma unroll
    for (int l = 0; l < CH / 256; ++l) {
        int g = e0 + l * 256 + tid;
        if (g < E) {
            int d = dst[g];
            int p = atomicAdd(&base[d >> BSH], 1);
            ebuf[p] = ((unsigned long long)(unsigned)d << 32) | (unsigned)src[g];
        }
    }
}

__global__ __launch_bounds__(256) void bucket_csr(const unsigned long long* __restrict__ ebuf,
                                                  const int* __restrict__ bcur, int N,
                                                  int2* __restrict__ rowbe,
                                                  int* __restrict__ csrc) {
    __shared__ int cnt[256];
    __shared__ int s[256];
    int b = blockIdx.x, tid = threadIdx.x;
    int beg = b * BCAP, end = bcur[b];
    int d0 = b << BSH;
    cnt[tid] = 0;
    __syncthreads();
    for (int i = beg + tid; i < end; i += 256)
        atomicAdd(&cnt[(int)(ebuf[i] >> 32) - d0], 1);
    __syncthreads();
    int v = cnt[tid];
    s[tid] = v;
    __syncthreads();
    for (int off = 1; off < 256; off <<= 1) {
        int t = (tid >= off) ? s[tid - off] : 0;
        __syncthreads();
        s[tid] += t;
        __syncthreads();
    }
    int excl = s[tid] - v;
    int d = d0 + tid;
    if (d < N) rowbe[d] = make_int2(beg + excl, beg + excl + v);
    cnt[tid] = beg + excl;
    __syncthreads();
    for (int i = beg + tid; i < end; i += 256) {
        unsigned long long e = ebuf[i];
        int p = atomicAdd(&cnt[(int)(e >> 32) - d0], 1);
        csrc[p] = (int)(e & 0xffffffffu);
    }
}

// ---------------- MFMA GEMM ----------------

template <bool AFP32, bool OBF, bool WIDEN>
__global__ __launch_bounds__(256) void gemm_mfma(const void* __restrict__ Asrc,
                                                 const unsigned short* __restrict__ Wt,
                                                 void* __restrict__ Y,
                                                 int N, int K, int M) {
    constexpr int WRF = WIDEN ? 4 : 2;
    constexpr int WCF = WIDEN ? 4 : 3;
    __shared__ __align__(16) unsigned short As[128][40];
    __shared__ __align__(16) unsigned short Bs[128][40];
    const int t = threadIdx.x;
    const int lane = t & 63, w = t >> 6;
    const int r0 = blockIdx.x * 128;
    const int wrow = WIDEN ? (w >> 1) * 64 : w * 32;
    const int wcol = WIDEN ? (w & 1) * 64 : 0;
    const int srow = t >> 1, shalf = t & 1;
    const int lr = lane & 15, lq = lane >> 4;
    f32x4 acc[WRF][WCF];
    #pragma unroll
    for (int f = 0; f < WRF; ++f)
        #pragma unroll
        for (int g = 0; g < WCF; ++g)
            acc[f][g] = (f32x4){0.f, 0.f, 0.f, 0.f};

    for (int k0 = 0; k0 < K; k0 += 32) {
        {
            int gr = r0 + srow;
            if (gr < N) {
                if constexpr (AFP32) {
                    const float* gp = (const float*)Asrc + (size_t)gr * K + k0 + shalf * 16;
                    float4 f0 = *(const float4*)(gp + 0);
                    float4 f1 = *(const float4*)(gp + 4);
                    float4 f2 = *(const float4*)(gp + 8);
                    float4 f3 = *(const float4*)(gp + 12);
                    *(uint4*)&As[srow][shalf * 16 + 0] =
                        make_uint4(pack2bf(f0.x, f0.y), pack2bf(f0.z, f0.w),
                                   pack2bf(f1.x, f1.y), pack2bf(f1.z, f1.w));
                    *(uint4*)&As[srow][shalf * 16 + 8] =
                        make_uint4(pack2bf(f2.x, f2.y), pack2bf(f2.z, f2.w),
                                   pack2bf(f3.x, f3.y), pack2bf(f3.z, f3.w));
                } else {
                    const uint4* gp = (const uint4*)((const unsigned short*)Asrc +
                                                     (size_t)gr * K + k0 + shalf * 16);
                    *(uint4*)&As[srow][shalf * 16 + 0] = gp[0];
                    *(uint4*)&As[srow][shalf * 16 + 8] = gp[1];
                }
            }
        }
        {
            int col = srow;
            if (col < M) {
                const uint4* gp = (const uint4*)(Wt + (size_t)col * K + k0 + shalf * 16);
                *(uint4*)&Bs[col][shalf * 16 + 0] = gp[0];
                *(uint4*)&Bs[col][shalf * 16 + 8] = gp[1];
            }
        }
        __syncthreads();
        bf16x8 af[WRF], bfr[WCF];
        #pragma unroll
        for (int f = 0; f < WRF; ++f)
            af[f] = *(const bf16x8*)&As[wrow + f * 16 + lr][lq * 8];
        #pragma unroll
        for (int g = 0; g < WCF; ++g)
            bfr[g] = *(const bf16x8*)&Bs[wcol + g * 16 + lr][lq * 8];
        #pragma unroll
        for (int f = 0; f < WRF; ++f)
            #pragma unroll
            for (int g = 0; g < WCF; ++g)
                acc[f][g] = __builtin_amdgcn_mfma_f32_16x16x32_bf16(af[f], bfr[g],
                                                                   acc[f][g], 0, 0, 0);
        __syncthreads();
    }
    #pragma unroll
    for (int f = 0; f < WRF; ++f) {
        #pragma unroll
        for (int g = 0; g < WCF; ++g) {
            int col = wcol + g * 16 + lr;
            if (!WIDEN && col >= M) continue;
            #pragma unroll
            for (int r = 0; r < 4; ++r) {
                int row = r0 + wrow + f * 16 + lq * 4 + r;
                if (row < N) {
                    if constexpr (OBF)
                        ((unsigned short*)Y)[(size_t)row * M + col] = f2bf(acc[f][g][r]);
                    else
                        ((float*)Y)[(size_t)row * M + col] = acc[f][g][r];
                }
            }
        }
    }
}

// ---------------- el / er ----------------

template <int H, int D, bool BF>
__global__ __launch_bounds__(256) void elr_kernel(const void* __restrict__ hv,
                                                  const float* __restrict__ al,
                                                  const float* __restrict__ ar,
                                                  float* __restrict__ el,
                                                  float* __restrict__ er, int N) {
    int g = blockIdx.x * blockDim.x + threadIdx.x;
    int n = g / H, hh = g % H;
    if (n >= N) return;
    float sl = 0.f, sr = 0.f;
    if constexpr (BF) {
        const unsigned short* hp = (const unsigned short*)hv + (size_t)n * H * D + hh * D;
        #pragma unroll
        for (int d = 0; d < D; d += 8) {
            uint4 u = *(const uint4*)(hp + d);
            float4 a0 = *(const float4*)(al + hh * D + d);
            float4 a1 = *(const float4*)(al + hh * D + d + 4);
            float4 r0 = *(const float4*)(ar + hh * D + d);
            float4 r1 = *(const float4*)(ar + hh * D + d + 4);
            float h0 = bflo(u.x), h1 = bfhi(u.x);
            float h2 = bflo(u.y), h3 = bfhi(u.y);
            float h4 = bflo(u.z), h5 = bfhi(u.z);
            float h6 = bflo(u.w), h7 = bfhi(u.w);
            sl += h0 * a0.x + h1 * a0.y + h2 * a0.z + h3 * a0.w
                + h4 * a1.x + h5 * a1.y + h6 * a1.z + h7 * a1.w;
            sr += h0 * r0.x + h1 * r0.y + h2 * r0.z + h3 * r0.w
                + h4 * r1.x + h5 * r1.y + h6 * r1.z + h7 * r1.w;
        }
    } else {
        const float* hp = (const float*)hv + (size_t)n * H * D + hh * D;
        #pragma unroll
        for (int d = 0; d < D; d += 4) {
            float4 hvv = *(const float4*)(hp + d);
            float4 av = *(const float4*)(al + hh * D + d);
            float4 rv = *(const float4*)(ar + hh * D + d);
            sl += hvv.x * av.x + hvv.y * av.y + hvv.z * av.z + hvv.w * av.w;
            sr += hvv.x * rv.x + hvv.y * rv.y + hvv.z * rv.z + hvv.w * rv.w;
        }
    }
    el[(size_t)n * H + hh] = sl;
    er[(size_t)n * H + hh] = sr;
}

// ---------------- aggregation: wave/dst, no max (shift-invariant) ----------------
// Round-8 structure: coop csrc chunk (64), shfl index broadcast, per-lane
// redundant exp (parallel, no cross-lane dependency), unroll-4 gathers.

template <int H, int D, bool ELU, bool BFW, bool OB>
__global__ __launch_bounds__(256) void agg_kernel(const void* __restrict__ hsrcv,
                                                  const float* __restrict__ el,
                                                  const float* __restrict__ er,
                                                  const float* __restrict__ bias,
                                                  const int2* __restrict__ rowbe,
                                                  const int* __restrict__ csrc,
                                                  void* __restrict__ outv, int N) {
    constexpr int HD = H * D;
    int wid = (int)(((size_t)blockIdx.x * blockDim.x + threadIdx.x) >> 6);
    int lane = threadIdx.x & 63;
    if (wid >= N) return;
    int eb = BFW ? lane * 2 : lane;
    bool active = BFW || (lane < HD);
    int head = active ? (eb / D) : 0;
    float er_d = er[(size_t)wid * H + head];
    int2 be = rowbe[wid];
    int beg = be.x, end = be.y;
    const unsigned int* hb = (const unsigned int*)hsrcv;
    const float* hf = (const float*)hsrcv;

    float denom = 0.f, a0 = 0.f, a1 = 0.f;

#define AGG_UPDATE(EV, HX, HY)                                                 \
    {                                                                          \
        float e_ = (EV) + er_d;                                                \
        e_ = (e_ > 0.f) ? e_ : 0.2f * e_;                                      \
        float ex_ = __expf(e_);                                                \
        denom += ex_;                                                          \
        a0 = fmaf(ex_, (HX), a0);                                              \
        a1 = fmaf(ex_, (HY), a1);                                              \
    }

    for (int chunk = beg; chunk < end; chunk += 64) {
        int cnt = min(64, end - chunk);
        int cs = (lane < cnt) ? csrc[chunk + lane] : 0;
        int j = 0;
        for (; j + 4 <= cnt; j += 4) {
            int s0 = __shfl(cs, j + 0), s1 = __shfl(cs, j + 1);
            int s2 = __shfl(cs, j + 2), s3 = __shfl(cs, j + 3);
            float e0 = el[(size_t)s0 * H + head];
            float e1 = el[(size_t)s1 * H + head];
            float e2 = el[(size_t)s2 * H + head];
            float e3 = el[(size_t)s3 * H + head];
            float h0x, h0y = 0.f, h1x, h1y = 0.f, h2x, h2y = 0.f, h3x, h3y = 0.f;
            if (BFW) {
                unsigned int v0 = hb[(size_t)s0 * (HD / 2) + lane];
                unsigned int v1 = hb[(size_t)s1 * (HD / 2) + lane];
                unsigned int v2 = hb[(size_t)s2 * (HD / 2) + lane];
                unsigned int v3 = hb[(size_t)s3 * (HD / 2) + lane];
                h0x = bflo(v0); h0y = bfhi(v0);
                h1x = bflo(v1); h1y = bfhi(v1);
                h2x = bflo(v2); h2y = bfhi(v2);
                h3x = bflo(v3); h3y = bfhi(v3);
            } else {
                h0x = active ? hf[(size_t)s0 * HD + eb] : 0.f;
                h1x = active ? hf[(size_t)s1 * HD + eb] : 0.f;
                h2x = active ? hf[(size_t)s2 * HD + eb] : 0.f;
                h3x = active ? hf[(size_t)s3 * HD + eb] : 0.f;
            }
            AGG_UPDATE(e0, h0x, h0y);
            AGG_UPDATE(e1, h1x, h1y);
            AGG_UPDATE(e2, h2x, h2y);
            AGG_UPDATE(e3, h3x, h3y);
        }
        for (; j < cnt; ++j) {
            int s0 = __shfl(cs, j);
            float e0 = el[(size_t)s0 * H + head];
            float hx, hy = 0.f;
            if (BFW) {
                unsigned int v0 = hb[(size_t)s0 * (HD / 2) + lane];
                hx = bflo(v0); hy = bfhi(v0);
            } else {
                hx = active ? hf[(size_t)s0 * HD + eb] : 0.f;
            }
            AGG_UPDATE(e0, hx, hy);
        }
    }
#undef AGG_UPDATE

    float inv = 1.f / (denom + 1e-9f);
    if (BFW) {
        float o0 = a0 * inv + bias[eb];
        float o1 = a1 * inv + bias[eb + 1];
        if (ELU) {
            o0 = (o0 > 0.f) ? o0 : expm1f(o0);
            o1 = (o1 > 0.f) ? o1 : expm1f(o1);
        }
        if constexpr (OB) {
            ((unsigned int*)outv)[(size_t)wid * (HD / 2) + lane] = pack2bf(o0, o1);
        } else {
            *(float2*)((float*)outv + (size_t)wid * HD + eb) = make_float2(o0, o1);
        }
    } else if (active) {
        float o = a0 * inv + bias[eb];
        if (ELU) o = (o > 0.f) ? o : expm1f(o);
        ((float*)outv)[(size_t)wid * HD + eb] = o;
    }
}

// ---------------- launch ----------------

extern "C" void kernel_launch(void* const* d_in, const int* in_sizes, int n_in,
                              void* d_out, int out_size, void* d_ws, size_t ws_size,
                              hipStream_t stream) {
    const float* x    = (const float*)d_in[0];
    const int* esrc   = (const int*)d_in[1];
    const int* edst   = (const int*)d_in[2];
    const float* W1   = (const float*)d_in[3];
    const float* al1  = (const float*)d_in[4];
    const float* ar1  = (const float*)d_in[5];
    const float* b1   = (const float*)d_in[6];
    const float* W2   = (const float*)d_in[7];
    const float* al2  = (const float*)d_in[8];
    const float* ar2  = (const float*)d_in[9];
    const float* b2   = (const float*)d_in[10];
    const float* W3   = (const float*)d_in[11];
    const float* al3  = (const float*)d_in[12];
    const float* ar3  = (const float*)d_in[13];
    const float* b3   = (const float*)d_in[14];

    const int FIN = 256;
    const int N = in_sizes[0] / FIN;    // 100000
    const int E = in_sizes[1];          // 1600000
    const int D1 = HEADS * HID;         // 128
    const int NBUCK = (N + 255) >> BSH; // 391

    unsigned short* Abf = (unsigned short*)d_ws;              // N*128 bf16
    unsigned short* Cbf = Abf + (size_t)N * D1;               // N*128 bf16
    float* A32 = (float*)(Cbf + (size_t)N * D1);              // N*40 fp32
    float* el  = A32 + (size_t)N * NCLS;                      // N*4
    float* er  = el + (size_t)N * HEADS;                      // N*4
    int2* rowbe = (int2*)(er + (size_t)N * HEADS);            // N int2
    int* csrc   = (int*)(rowbe + N);                          // NBUCK*BCAP
    int* bcur   = csrc + (size_t)NBUCK * BCAP;                // NBUCK
    unsigned short* Wt1 = (unsigned short*)(bcur + NBUCK);    // 128*256
    unsigned short* Wt2 = Wt1 + 128 * 256;                    // 128*128
    unsigned short* Wt3 = Wt2 + 128 * 128;                    // 40*128
    unsigned long long* ebuf = (unsigned long long*)Abf;      // NBUCK*BCAP*8 = 19.2MB

    int WGRID = (int)(((size_t)N * 64 + 255) / 256);
    int PB = (E + CH - 1) / CH;
    int GB = (N + 127) / 128;

    // ---- fused prep (Wt transposes + bcur init) ----
    prep_all<<<(54272 + NBUCK + 255) / 256, 256, 0, stream>>>(W1, W2, W3, Wt1, Wt2, Wt3,
                                                              NBUCK, bcur);

    // ---- CSR build (fixed-capacity buckets) ----
    bucket_partition<<<PB, 256, 0, stream>>>(esrc, edst, E, NBUCK, bcur, ebuf);
    bucket_csr<<<NBUCK, 256, 0, stream>>>(ebuf, bcur, N, rowbe, csrc);

    // ---- layer 1 ----
    gemm_mfma<true, true, true><<<GB, 256, 0, stream>>>(x, Wt1, Abf, N, FIN, D1);
    elr_kernel<HEADS, HID, true><<<(N * HEADS + 255) / 256, 256, 0, stream>>>(Abf, al1, ar1, el, er, N);
    agg_kernel<HEADS, HID, true, true, true><<<WGRID, 256, 0, stream>>>(Abf, el, er, b1, rowbe, csrc, Cbf, N);

    // ---- layer 2 ----
    gemm_mfma<false, true, true><<<GB, 256, 0, stream>>>(Cbf, Wt2, Abf, N, D1, D1);
    elr_kernel<HEADS, HID, true><<<(N * HEADS + 255) / 256, 256, 0, stream>>>(Abf, al2, ar2, el, er, N);
    agg_kernel<HEADS, HID, true, true, true><<<WGRID, 256, 0, stream>>>(Abf, el, er, b2, rowbe, csrc, Cbf, N);

    // ---- layer 3 ----
    gemm_mfma<false, false, false><<<GB, 256, 0, stream>>>(Cbf, Wt3, A32, N, D1, NCLS);
    elr_kernel<1, NCLS, false><<<(N + 255) / 256, 256, 0, stream>>>(A32, al3, ar3, el, er, N);
    agg_kernel<1, NCLS, false, false, false><<<WGRID, 256, 0, stream>>>(A32, el, er, b3, rowbe, csrc, d_out, N);
}

// Round 11
// 346.479 us; speedup vs baseline: 1.4993x; 1.0479x over previous
//
#include <hip/hip_runtime.h>
#include <math.h>

// GAT 3-layer. Round 11: elr fused into gemm epilogue (el/er from fp32 acc via
// shfl_xor reduction over the 16-lane col group; head = g-pair, no cross-wave
// combine needed). Otherwise identical to round 10.

#define HEADS 4
#define HID   32
#define NCLS  40
#define BSH   8
#define CH    4096
#define BCAP  6144

typedef __attribute__((ext_vector_type(8))) short bf16x8;
typedef __attribute__((ext_vector_type(4))) float f32x4;

static __device__ __forceinline__ unsigned short f2bf(float f) {
    unsigned int u = __float_as_uint(f);
    u += 0x7fffu + ((u >> 16) & 1u);   // RNE
    return (unsigned short)(u >> 16);
}
static __device__ __forceinline__ float bflo(unsigned int v) {
    return __uint_as_float(v << 16);
}
static __device__ __forceinline__ float bfhi(unsigned int v) {
    return __uint_as_float(v & 0xffff0000u);
}
static __device__ __forceinline__ unsigned int pack2bf(float lo, float hi) {
    return (unsigned int)f2bf(lo) | ((unsigned int)f2bf(hi) << 16);
}

// ---------------- fused prep: Wt1/Wt2/Wt3 transpose+cast, bcur init ----------------

__global__ __launch_bounds__(256) void prep_all(const float* __restrict__ W1,
                                                const float* __restrict__ W2,
                                                const float* __restrict__ W3,
                                                unsigned short* __restrict__ Wt1,
                                                unsigned short* __restrict__ Wt2,
                                                unsigned short* __restrict__ Wt3,
                                                int NBUCK, int* __restrict__ bcur) {
    int g = blockIdx.x * 256 + threadIdx.x;
    if (g < 32768) {                       // Wt1: [128][256]
        int m = g >> 8, k = g & 255;
        Wt1[g] = f2bf(W1[(size_t)k * 128 + m]);
    } else if (g < 49152) {                // Wt2: [128][128]
        int g2 = g - 32768;
        int m = g2 >> 7, k = g2 & 127;
        Wt2[g2] = f2bf(W2[(size_t)k * 128 + m]);
    } else if (g < 54272) {                // Wt3: [40][128]
        int g3 = g - 49152;
        int m = g3 >> 7, k = g3 & 127;
        Wt3[g3] = f2bf(W3[(size_t)k * 40 + m]);
    } else if (g - 54272 < NBUCK) {
        int b = g - 54272;
        bcur[b] = b * BCAP;
    }
}

// ---------------- bucketed CSR build (fixed-capacity buckets) ----------------

__global__ __launch_bounds__(256) void bucket_partition(const int* __restrict__ src,
                                                        const int* __restrict__ dst, int E,
                                                        int NBUCK, int* __restrict__ bcur,
                                                        unsigned long long* __restrict__ ebuf) {
    __shared__ int h[512];
    __shared__ int base[512];
    int tid = threadIdx.x;
    int e0 = blockIdx.x * CH;
    for (int i = tid; i < NBUCK; i += 256) h[i] = 0;
    __syncthreads();
    #pragma unroll
    for (int l = 0; l < CH / 256; ++l) {
        int g = e0 + l * 256 + tid;
        if (g < E) atomicAdd(&h[dst[g] >> BSH], 1);
    }
    __syncthreads();
    for (int i = tid; i < NBUCK; i += 256) {
        int c = h[i];
        if (c) base[i] = atomicAdd(&bcur[i], c);
    }
    __syncthreads();
    #pragma unroll
    for (int l = 0; l < CH / 256; ++l) {
        int g = e0 + l * 256 + tid;
        if (g < E) {
            int d = dst[g];
            int p = atomicAdd(&base[d >> BSH], 1);
            ebuf[p] = ((unsigned long long)(unsigned)d << 32) | (unsigned)src[g];
        }
    }
}

__global__ __launch_bounds__(256) void bucket_csr(const unsigned long long* __restrict__ ebuf,
                                                  const int* __restrict__ bcur, int N,
                                                  int2* __restrict__ rowbe,
                                                  int* __restrict__ csrc) {
    __shared__ int cnt[256];
    __shared__ int s[256];
    int b = blockIdx.x, tid = threadIdx.x;
    int beg = b * BCAP, end = bcur[b];
    int d0 = b << BSH;
    cnt[tid] = 0;
    __syncthreads();
    for (int i = beg + tid; i < end; i += 256)
        atomicAdd(&cnt[(int)(ebuf[i] >> 32) - d0], 1);
    __syncthreads();
    int v = cnt[tid];
    s[tid] = v;
    __syncthreads();
    for (int off = 1; off < 256; off <<= 1) {
        int t = (tid >= off) ? s[tid - off] : 0;
        __syncthreads();
        s[tid] += t;
        __syncthreads();
    }
    int excl = s[tid] - v;
    int d = d0 + tid;
    if (d < N) rowbe[d] = make_int2(beg + excl, beg + excl + v);
    cnt[tid] = beg + excl;
    __syncthreads();
    for (int i = beg + tid; i < end; i += 256) {
        unsigned long long e = ebuf[i];
        int p = atomicAdd(&cnt[(int)(e >> 32) - d0], 1);
        csrc[p] = (int)(e & 0xffffffffu);
    }
}

// ---------------- MFMA GEMM with fused el/er epilogue ----------------
// el[row*H+head] = sum_c h[row][c]*al[c] computed from fp32 acc:
// per lane, per (f,r): 2-col partials per head (g-pairs), 4x shfl_xor reduce
// over the 16 lr lanes (lane bits 0-3; one head's 32 cols = g-pair x 16 lr).

template <bool AFP32, bool OBF, bool WIDEN>
__global__ __launch_bounds__(256) void gemm_mfma(const void* __restrict__ Asrc,
                                                 const unsigned short* __restrict__ Wt,
                                                 void* __restrict__ Y,
                                                 const float* __restrict__ al,
                                                 const float* __restrict__ ar,
                                                 float* __restrict__ el,
                                                 float* __restrict__ er,
                                                 int N, int K, int M) {
    constexpr int WRF = WIDEN ? 4 : 2;
    constexpr int WCF = WIDEN ? 4 : 3;
    constexpr int H   = WIDEN ? 4 : 1;
    __shared__ __align__(16) unsigned short As[128][40];
    __shared__ __align__(16) unsigned short Bs[128][40];
    const int t = threadIdx.x;
    const int lane = t & 63, w = t >> 6;
    const int r0 = blockIdx.x * 128;
    const int wrow = WIDEN ? (w >> 1) * 64 : w * 32;
    const int wcol = WIDEN ? (w & 1) * 64 : 0;
    const int srow = t >> 1, shalf = t & 1;
    const int lr = lane & 15, lq = lane >> 4;
    f32x4 acc[WRF][WCF];
    #pragma unroll
    for (int f = 0; f < WRF; ++f)
        #pragma unroll
        for (int g = 0; g < WCF; ++g)
            acc[f][g] = (f32x4){0.f, 0.f, 0.f, 0.f};

    for (int k0 = 0; k0 < K; k0 += 32) {
        {
            int gr = r0 + srow;
            if (gr < N) {
                if constexpr (AFP32) {
                    const float* gp = (const float*)Asrc + (size_t)gr * K + k0 + shalf * 16;
                    float4 f0 = *(const float4*)(gp + 0);
                    float4 f1 = *(const float4*)(gp + 4);
                    float4 f2 = *(const float4*)(gp + 8);
                    float4 f3 = *(const float4*)(gp + 12);
                    *(uint4*)&As[srow][shalf * 16 + 0] =
                        make_uint4(pack2bf(f0.x, f0.y), pack2bf(f0.z, f0.w),
                                   pack2bf(f1.x, f1.y), pack2bf(f1.z, f1.w));
                    *(uint4*)&As[srow][shalf * 16 + 8] =
                        make_uint4(pack2bf(f2.x, f2.y), pack2bf(f2.z, f2.w),
                                   pack2bf(f3.x, f3.y), pack2bf(f3.z, f3.w));
                } else {
                    const uint4* gp = (const uint4*)((const unsigned short*)Asrc +
                                                     (size_t)gr * K + k0 + shalf * 16);
                    *(uint4*)&As[srow][shalf * 16 + 0] = gp[0];
                    *(uint4*)&As[srow][shalf * 16 + 8] = gp[1];
                }
            }
        }
        {
            int col = srow;
            if (col < M) {
                const uint4* gp = (const uint4*)(Wt + (size_t)col * K + k0 + shalf * 16);
                *(uint4*)&Bs[col][shalf * 16 + 0] = gp[0];
                *(uint4*)&Bs[col][shalf * 16 + 8] = gp[1];
            }
        }
        __syncthreads();
        bf16x8 af[WRF], bfr[WCF];
        #pragma unroll
        for (int f = 0; f < WRF; ++f)
            af[f] = *(const bf16x8*)&As[wrow + f * 16 + lr][lq * 8];
        #pragma unroll
        for (int g = 0; g < WCF; ++g)
            bfr[g] = *(const bf16x8*)&Bs[wcol + g * 16 + lr][lq * 8];
        #pragma unroll
        for (int f = 0; f < WRF; ++f)
            #pragma unroll
            for (int g = 0; g < WCF; ++g)
                acc[f][g] = __builtin_amdgcn_mfma_f32_16x16x32_bf16(af[f], bfr[g],
                                                                   acc[f][g], 0, 0, 0);
        __syncthreads();
    }

    // ---- C write ----
    #pragma unroll
    for (int f = 0; f < WRF; ++f) {
        #pragma unroll
        for (int g = 0; g < WCF; ++g) {
            int col = wcol + g * 16 + lr;
            if (!WIDEN && col >= M) continue;
            #pragma unroll
            for (int r = 0; r < 4; ++r) {
                int row = r0 + wrow + f * 16 + lq * 4 + r;
                if (row < N) {
                    if constexpr (OBF)
                        ((unsigned short*)Y)[(size_t)row * M + col] = f2bf(acc[f][g][r]);
                    else
                        ((float*)Y)[(size_t)row * M + col] = acc[f][g][r];
                }
            }
        }
    }

    // ---- fused el/er ----
    float alv[WCF], arv[WCF];
    #pragma unroll
    for (int g = 0; g < WCF; ++g) {
        int col = wcol + g * 16 + lr;
        bool ok = WIDEN || (col < M);
        alv[g] = ok ? al[col] : 0.f;
        arv[g] = ok ? ar[col] : 0.f;
    }
    if constexpr (WIDEN) {
        const int hlo = wcol >> 5;   // head of g0,g1; head hlo+1 = g2,g3
        #pragma unroll
        for (int f = 0; f < WRF; ++f) {
            #pragma unroll
            for (int r = 0; r < 4; ++r) {
                float pal0 = acc[f][0][r] * alv[0] + acc[f][1][r] * alv[1];
                float par0 = acc[f][0][r] * arv[0] + acc[f][1][r] * arv[1];
                float pal1 = acc[f][2][r] * alv[2] + acc[f][3][r] * alv[3];
                float par1 = acc[f][2][r] * arv[2] + acc[f][3][r] * arv[3];
                #pragma unroll
                for (int m = 1; m < 16; m <<= 1) {
                    pal0 += __shfl_xor(pal0, m);
                    par0 += __shfl_xor(par0, m);
                    pal1 += __shfl_xor(pal1, m);
                    par1 += __shfl_xor(par1, m);
                }
                int row = r0 + wrow + f * 16 + lq * 4 + r;
                if (lr == 0 && row < N) {
                    el[(size_t)row * H + hlo] = pal0;
                    er[(size_t)row * H + hlo] = par0;
                    el[(size_t)row * H + hlo + 1] = pal1;
                    er[(size_t)row * H + hlo + 1] = par1;
                }
            }
        }
    } else {
        #pragma unroll
        for (int f = 0; f < WRF; ++f) {
            #pragma unroll
            for (int r = 0; r < 4; ++r) {
                float pal = acc[f][0][r] * alv[0] + acc[f][1][r] * alv[1]
                          + acc[f][2][r] * alv[2];
                float par = acc[f][0][r] * arv[0] + acc[f][1][r] * arv[1]
                          + acc[f][2][r] * arv[2];
                #pragma unroll
                for (int m = 1; m < 16; m <<= 1) {
                    pal += __shfl_xor(pal, m);
                    par += __shfl_xor(par, m);
                }
                int row = r0 + wrow + f * 16 + lq * 4 + r;
                if (lr == 0 && row < N) {
                    el[row] = pal;
                    er[row] = par;
                }
            }
        }
    }
}

// ---------------- aggregation: wave/dst, no max (shift-invariant) ----------------

template <int H, int D, bool ELU, bool BFW, bool OB>
__global__ __launch_bounds__(256) void agg_kernel(const void* __restrict__ hsrcv,
                                                  const float* __restrict__ el,
                                                  const float* __restrict__ er,
                                                  const float* __restrict__ bias,
                                                  const int2* __restrict__ rowbe,
                                                  const int* __restrict__ csrc,
                                                  void* __restrict__ outv, int N) {
    constexpr int HD = H * D;
    int wid = (int)(((size_t)blockIdx.x * blockDim.x + threadIdx.x) >> 6);
    int lane = threadIdx.x & 63;
    if (wid >= N) return;
    int eb = BFW ? lane * 2 : lane;
    bool active = BFW || (lane < HD);
    int head = active ? (eb / D) : 0;
    float er_d = er[(size_t)wid * H + head];
    int2 be = rowbe[wid];
    int beg = be.x, end = be.y;
    const unsigned int* hb = (const unsigned int*)hsrcv;
    const float* hf = (const float*)hsrcv;

    float denom = 0.f, a0 = 0.f, a1 = 0.f;

#define AGG_UPDATE(EV, HX, HY)                                                 \
    {                                                                          \
        float e_ = (EV) + er_d;                                                \
        e_ = (e_ > 0.f) ? e_ : 0.2f * e_;                                      \
        float ex_ = __expf(e_);                                                \
        denom += ex_;                                                          \
        a0 = fmaf(ex_, (HX), a0);                                              \
        a1 = fmaf(ex_, (HY), a1);                                              \
    }

    for (int chunk = beg; chunk < end; chunk += 64) {
        int cnt = min(64, end - chunk);
        int cs = (lane < cnt) ? csrc[chunk + lane] : 0;
        int j = 0;
        for (; j + 4 <= cnt; j += 4) {
            int s0 = __shfl(cs, j + 0), s1 = __shfl(cs, j + 1);
            int s2 = __shfl(cs, j + 2), s3 = __shfl(cs, j + 3);
            float e0 = el[(size_t)s0 * H + head];
            float e1 = el[(size_t)s1 * H + head];
            float e2 = el[(size_t)s2 * H + head];
            float e3 = el[(size_t)s3 * H + head];
            float h0x, h0y = 0.f, h1x, h1y = 0.f, h2x, h2y = 0.f, h3x, h3y = 0.f;
            if (BFW) {
                unsigned int v0 = hb[(size_t)s0 * (HD / 2) + lane];
                unsigned int v1 = hb[(size_t)s1 * (HD / 2) + lane];
                unsigned int v2 = hb[(size_t)s2 * (HD / 2) + lane];
                unsigned int v3 = hb[(size_t)s3 * (HD / 2) + lane];
                h0x = bflo(v0); h0y = bfhi(v0);
                h1x = bflo(v1); h1y = bfhi(v1);
                h2x = bflo(v2); h2y = bfhi(v2);
                h3x = bflo(v3); h3y = bfhi(v3);
            } else {
                h0x = active ? hf[(size_t)s0 * HD + eb] : 0.f;
                h1x = active ? hf[(size_t)s1 * HD + eb] : 0.f;
                h2x = active ? hf[(size_t)s2 * HD + eb] : 0.f;
                h3x = active ? hf[(size_t)s3 * HD + eb] : 0.f;
            }
            AGG_UPDATE(e0, h0x, h0y);
            AGG_UPDATE(e1, h1x, h1y);
            AGG_UPDATE(e2, h2x, h2y);
            AGG_UPDATE(e3, h3x, h3y);
        }
        for (; j < cnt; ++j) {
            int s0 = __shfl(cs, j);
            float e0 = el[(size_t)s0 * H + head];
            float hx, hy = 0.f;
            if (BFW) {
                unsigned int v0 = hb[(size_t)s0 * (HD / 2) + lane];
                hx = bflo(v0); hy = bfhi(v0);
            } else {
                hx = active ? hf[(size_t)s0 * HD + eb] : 0.f;
            }
            AGG_UPDATE(e0, hx, hy);
        }
    }
#undef AGG_UPDATE

    float inv = 1.f / (denom + 1e-9f);
    if (BFW) {
        float o0 = a0 * inv + bias[eb];
        float o1 = a1 * inv + bias[eb + 1];
        if (ELU) {
            o0 = (o0 > 0.f) ? o0 : expm1f(o0);
            o1 = (o1 > 0.f) ? o1 : expm1f(o1);
        }
        if constexpr (OB) {
            ((unsigned int*)outv)[(size_t)wid * (HD / 2) + lane] = pack2bf(o0, o1);
        } else {
            *(float2*)((float*)outv + (size_t)wid * HD + eb) = make_float2(o0, o1);
        }
    } else if (active) {
        float o = a0 * inv + bias[eb];
        if (ELU) o = (o > 0.f) ? o : expm1f(o);
        ((float*)outv)[(size_t)wid * HD + eb] = o;
    }
}

// ---------------- launch ----------------

extern "C" void kernel_launch(void* const* d_in, const int* in_sizes, int n_in,
                              void* d_out, int out_size, void* d_ws, size_t ws_size,
                              hipStream_t stream) {
    const float* x    = (const float*)d_in[0];
    const int* esrc   = (const int*)d_in[1];
    const int* edst   = (const int*)d_in[2];
    const float* W1   = (const float*)d_in[3];
    const float* al1  = (const float*)d_in[4];
    const float* ar1  = (const float*)d_in[5];
    const float* b1   = (const float*)d_in[6];
    const float* W2   = (const float*)d_in[7];
    const float* al2  = (const float*)d_in[8];
    const float* ar2  = (const float*)d_in[9];
    const float* b2   = (const float*)d_in[10];
    const float* W3   = (const float*)d_in[11];
    const float* al3  = (const float*)d_in[12];
    const float* ar3  = (const float*)d_in[13];
    const float* b3   = (const float*)d_in[14];

    const int FIN = 256;
    const int N = in_sizes[0] / FIN;    // 100000
    const int E = in_sizes[1];          // 1600000
    const int D1 = HEADS * HID;         // 128
    const int NBUCK = (N + 255) >> BSH; // 391

    unsigned short* Abf = (unsigned short*)d_ws;              // N*128 bf16
    unsigned short* Cbf = Abf + (size_t)N * D1;               // N*128 bf16
    float* A32 = (float*)(Cbf + (size_t)N * D1);              // N*40 fp32
    float* el  = A32 + (size_t)N * NCLS;                      // N*4
    float* er  = el + (size_t)N * HEADS;                      // N*4
    int2* rowbe = (int2*)(er + (size_t)N * HEADS);            // N int2
    int* csrc   = (int*)(rowbe + N);                          // NBUCK*BCAP
    int* bcur   = csrc + (size_t)NBUCK * BCAP;                // NBUCK
    unsigned short* Wt1 = (unsigned short*)(bcur + NBUCK);    // 128*256
    unsigned short* Wt2 = Wt1 + 128 * 256;                    // 128*128
    unsigned short* Wt3 = Wt2 + 128 * 128;                    // 40*128
    unsigned long long* ebuf = (unsigned long long*)Abf;      // NBUCK*BCAP*8 = 19.2MB

    int WGRID = (int)(((size_t)N * 64 + 255) / 256);
    int PB = (E + CH - 1) / CH;
    int GB = (N + 127) / 128;

    // ---- fused prep (Wt transposes + bcur init) ----
    prep_all<<<(54272 + NBUCK + 255) / 256, 256, 0, stream>>>(W1, W2, W3, Wt1, Wt2, Wt3,
                                                              NBUCK, bcur);

    // ---- CSR build (fixed-capacity buckets) ----
    bucket_partition<<<PB, 256, 0, stream>>>(esrc, edst, E, NBUCK, bcur, ebuf);
    bucket_csr<<<NBUCK, 256, 0, stream>>>(ebuf, bcur, N, rowbe, csrc);

    // ---- layer 1 ----
    gemm_mfma<true, true, true><<<GB, 256, 0, stream>>>(x, Wt1, Abf, al1, ar1, el, er, N, FIN, D1);
    agg_kernel<HEADS, HID, true, true, true><<<WGRID, 256, 0, stream>>>(Abf, el, er, b1, rowbe, csrc, Cbf, N);

    // ---- layer 2 ----
    gemm_mfma<false, true, true><<<GB, 256, 0, stream>>>(Cbf, Wt2, Abf, al2, ar2, el, er, N, D1, D1);
    agg_kernel<HEADS, HID, true, true, true><<<WGRID, 256, 0, stream>>>(Abf, el, er, b2, rowbe, csrc, Cbf, N);

    // ---- layer 3 ----
    gemm_mfma<false, false, false><<<GB, 256, 0, stream>>>(Cbf, Wt3, A32, al3, ar3, el, er, N, D1, NCLS);
    agg_kernel<1, NCLS, false, false, false><<<WGRID, 256, 0, stream>>>(A32, el, er, b3, rowbe, csrc, d_out, N);
}

// Round 12
// 327.253 us; speedup vs baseline: 1.5874x; 1.0588x over previous
//
#include <hip/hip_runtime.h>
#include <math.h>

// GAT 3-layer. Round 12:
//  - gemm_mfma: 2-phase double-buffered pipeline (issue loads early, MFMA on
//    cur buffer, vmcnt+ds_write to other buffer, 1 barrier/step).
//  - el/er fused as extra GEMM B-columns: el = x.(W al_h) with aw = W al_h
//    precomputed per head (bf16). No shfl epilogue.

#define HEADS 4
#define HID   32
#define NCLS  40
#define BSH   8
#define CH    4096
#define BCAP  6144

typedef __attribute__((ext_vector_type(8))) short bf16x8;
typedef __attribute__((ext_vector_type(4))) float f32x4;

static __device__ __forceinline__ unsigned short f2bf(float f) {
    unsigned int u = __float_as_uint(f);
    u += 0x7fffu + ((u >> 16) & 1u);   // RNE
    return (unsigned short)(u >> 16);
}
static __device__ __forceinline__ float bflo(unsigned int v) {
    return __uint_as_float(v << 16);
}
static __device__ __forceinline__ float bfhi(unsigned int v) {
    return __uint_as_float(v & 0xffff0000u);
}
static __device__ __forceinline__ unsigned int pack2bf(float lo, float hi) {
    return (unsigned int)f2bf(lo) | ((unsigned int)f2bf(hi) << 16);
}

// ---------------- fused prep: Wt transposes, aw = W.al_h / W.ar_h, bcur ----------------

__global__ __launch_bounds__(256) void prep_all(const float* __restrict__ W1,
                                                const float* __restrict__ W2,
                                                const float* __restrict__ W3,
                                                const float* __restrict__ al1,
                                                const float* __restrict__ ar1,
                                                const float* __restrict__ al2,
                                                const float* __restrict__ ar2,
                                                const float* __restrict__ al3,
                                                const float* __restrict__ ar3,
                                                unsigned short* __restrict__ Wt1,
                                                unsigned short* __restrict__ Wt2,
                                                unsigned short* __restrict__ Wt3,
                                                unsigned short* __restrict__ aw1,
                                                unsigned short* __restrict__ aw2,
                                                unsigned short* __restrict__ aw3,
                                                int NBUCK, int* __restrict__ bcur) {
    int g = blockIdx.x * 256 + threadIdx.x;
    if (g < 32768) {                        // Wt1 [128][256]
        int m = g >> 8, k = g & 255;
        Wt1[g] = f2bf(W1[(size_t)k * 128 + m]);
    } else if (g < 49152) {                 // Wt2 [128][128]
        int i = g - 32768;
        int m = i >> 7, k = i & 127;
        Wt2[i] = f2bf(W2[(size_t)k * 128 + m]);
    } else if (g < 54272) {                 // Wt3 [40][128]
        int i = g - 49152;
        int m = i >> 7, k = i & 127;
        Wt3[i] = f2bf(W3[(size_t)k * 40 + m]);
    } else if (g < 56320) {                 // aw1: v(0-7) x 256; v<4 el-head v, else er-head v-4
        int i = g - 54272;
        int v = i >> 8, k = i & 255;
        const float* a = (v < 4) ? al1 : ar1;
        int h = v & 3;
        float s = 0.f;
        for (int d = 0; d < 32; ++d) s += W1[(size_t)k * 128 + h * 32 + d] * a[h * 32 + d];
        aw1[v * 256 + k] = f2bf(s);
    } else if (g < 57344) {                 // aw2: v(0-7) x 128
        int i = g - 56320;
        int v = i >> 7, k = i & 127;
        const float* a = (v < 4) ? al2 : ar2;
        int h = v & 3;
        float s = 0.f;
        for (int d = 0; d < 32; ++d) s += W2[(size_t)k * 128 + h * 32 + d] * a[h * 32 + d];
        aw2[v * 128 + k] = f2bf(s);
    } else if (g < 57600) {                 // aw3: v(0-1) x 128
        int i = g - 57344;
        int v = i >> 7, k = i & 127;
        const float* a = v ? ar3 : al3;
        float s = 0.f;
        for (int m = 0; m < 40; ++m) s += W3[(size_t)k * 40 + m] * a[m];
        aw3[v * 128 + k] = f2bf(s);
    } else if (g - 57600 < NBUCK) {
        int b = g - 57600;
        bcur[b] = b * BCAP;
    }
}

// ---------------- bucketed CSR build (fixed-capacity buckets) ----------------

__global__ __launch_bounds__(256) void bucket_partition(const int* __restrict__ src,
                                                        const int* __restrict__ dst, int E,
                                                        int NBUCK, int* __restrict__ bcur,
                                                        unsigned long long* __restrict__ ebuf) {
    __shared__ int h[512];
    __shared__ int base[512];
    int tid = threadIdx.x;
    int e0 = blockIdx.x * CH;
    for (int i = tid; i < NBUCK; i += 256) h[i] = 0;
    __syncthreads();
    #pragma unroll
    for (int l = 0; l < CH / 256; ++l) {
        int g = e0 + l * 256 + tid;
        if (g < E) atomicAdd(&h[dst[g] >> BSH], 1);
    }
    __syncthreads();
    for (int i = tid; i < NBUCK; i += 256) {
        int c = h[i];
        if (c) base[i] = atomicAdd(&bcur[i], c);
    }
    __syncthreads();
    #pragma unroll
    for (int l = 0; l < CH / 256; ++l) {
        int g = e0 + l * 256 + tid;
        if (g < E) {
            int d = dst[g];
            int p = atomicAdd(&base[d >> BSH], 1);
            ebuf[p] = ((unsigned long long)(unsigned)d << 32) | (unsigned)src[g];
        }
    }
}

__global__ __launch_bounds__(256) void bucket_csr(const unsigned long long* __restrict__ ebuf,
                                                  const int* __restrict__ bcur, int N,
                                                  int2* __restrict__ rowbe,
                                                  int* __restrict__ csrc) {
    __shared__ int cnt[256];
    __shared__ int s[256];
    int b = blockIdx.x, tid = threadIdx.x;
    int beg = b * BCAP, end = bcur[b];
    int d0 = b << BSH;
    cnt[tid] = 0;
    __syncthreads();
    for (int i = beg + tid; i < end; i += 256)
        atomicAdd(&cnt[(int)(ebuf[i] >> 32) - d0], 1);
    __syncthreads();
    int v = cnt[tid];
    s[tid] = v;
    __syncthreads();
    for (int off = 1; off < 256; off <<= 1) {
        int t = (tid >= off) ? s[tid - off] : 0;
        __syncthreads();
        s[tid] += t;
        __syncthreads();
    }
    int excl = s[tid] - v;
    int d = d0 + tid;
    if (d < N) rowbe[d] = make_int2(beg + excl, beg + excl + v);
    cnt[tid] = beg + excl;
    __syncthreads();
    for (int i = beg + tid; i < end; i += 256) {
        unsigned long long e = ebuf[i];
        int p = atomicAdd(&cnt[(int)(e >> 32) - d0], 1);
        csrc[p] = (int)(e & 0xffffffffu);
    }
}

// ---------------- MFMA GEMM: 2-phase dbuf + attn columns ----------------
// WIDEN (M=128): 4 waves as 2x2 quadrants 64x64; attn cols 128-135 via extra
// fragment on odd waves (el heads 0-3 = cols 128-131, er = 132-135).
// !WIDEN (M=40): wave w = rows w*32..+31, cols 0-47; attn cols 40,41 inside
// the 3rd fragment for free.

template <bool AFP32, bool OBF, bool WIDEN>
__global__ __launch_bounds__(256) void gemm_mfma(const void* __restrict__ Asrc,
                                                 const unsigned short* __restrict__ Wt,
                                                 const unsigned short* __restrict__ aw,
                                                 void* __restrict__ Y,
                                                 float* __restrict__ el,
                                                 float* __restrict__ er,
                                                 int N, int K, int M) {
    constexpr int WRF = WIDEN ? 4 : 2;
    constexpr int WCF = WIDEN ? 4 : 3;
    constexpr int BR  = WIDEN ? 144 : 48;
    constexpr int EBASE = WIDEN ? 128 : 0;
    __shared__ __align__(16) unsigned short As[2][128][40];
    __shared__ __align__(16) unsigned short Bs[2][BR][40];
    const int t = threadIdx.x;
    const int lane = t & 63, w = t >> 6;
    const int r0 = blockIdx.x * 128;
    const int wrow = WIDEN ? (w >> 1) * 64 : w * 32;
    const int wcol = WIDEN ? (w & 1) * 64 : 0;
    const int srow = t >> 1, shalf = t & 1;
    const int lr = lane & 15, lq = lane >> 4;
    const bool xw = WIDEN && (w & 1);
    const int gr = r0 + srow;
    const bool arow_ok = gr < N;
    const bool brow_ok = srow < (WIDEN ? M : M + 2);

    f32x4 acc[WRF][WCF];
    #pragma unroll
    for (int f = 0; f < WRF; ++f)
        #pragma unroll
        for (int g = 0; g < WCF; ++g)
            acc[f][g] = (f32x4){0.f, 0.f, 0.f, 0.f};
    f32x4 acc4[WRF];
    #pragma unroll
    for (int f = 0; f < WRF; ++f) acc4[f] = (f32x4){0.f, 0.f, 0.f, 0.f};

    const int nsteps = K >> 5;
    float4 xf0 = {0,0,0,0}, xf1 = {0,0,0,0}, xf2 = {0,0,0,0}, xf3 = {0,0,0,0};
    uint4 xu0 = {0,0,0,0}, xu1 = {0,0,0,0};
    uint4 bu0, bu1, eu0, eu1;

#define G_LOAD(K0)                                                                       \
    {                                                                                    \
        if (arow_ok) {                                                                   \
            if constexpr (AFP32) {                                                       \
                const float* gp = (const float*)Asrc + (size_t)gr * K + (K0) + shalf*16; \
                xf0 = *(const float4*)(gp + 0);  xf1 = *(const float4*)(gp + 4);         \
                xf2 = *(const float4*)(gp + 8);  xf3 = *(const float4*)(gp + 12);        \
            } else {                                                                     \
                const uint4* gp = (const uint4*)((const unsigned short*)Asrc +           \
                                                 (size_t)gr * K + (K0) + shalf * 16);    \
                xu0 = gp[0]; xu1 = gp[1];                                                \
            }                                                                            \
        }                                                                                \
        if (brow_ok) {                                                                   \
            const unsigned short* bp = (srow < M) ? (Wt + (size_t)srow * K)              \
                                                  : (aw + (size_t)(srow - M) * K);       \
            const uint4* gp = (const uint4*)(bp + (K0) + shalf * 16);                    \
            bu0 = gp[0]; bu1 = gp[1];                                                    \
        }                                                                                \
        if (WIDEN && t < 16) {                                                           \
            const uint4* gp = (const uint4*)(aw + (size_t)(t >> 1) * K + (K0) + (t & 1) * 16); \
            eu0 = gp[0]; eu1 = gp[1];                                                    \
        }                                                                                \
    }

#define L_STORE(B)                                                                       \
    {                                                                                    \
        if constexpr (AFP32) {                                                           \
            *(uint4*)&As[B][srow][shalf * 16 + 0] =                                      \
                make_uint4(pack2bf(xf0.x, xf0.y), pack2bf(xf0.z, xf0.w),                 \
                           pack2bf(xf1.x, xf1.y), pack2bf(xf1.z, xf1.w));                \
            *(uint4*)&As[B][srow][shalf * 16 + 8] =                                      \
                make_uint4(pack2bf(xf2.x, xf2.y), pack2bf(xf2.z, xf2.w),                 \
                           pack2bf(xf3.x, xf3.y), pack2bf(xf3.z, xf3.w));                \
        } else {                                                                         \
            *(uint4*)&As[B][srow][shalf * 16 + 0] = xu0;                                 \
            *(uint4*)&As[B][srow][shalf * 16 + 8] = xu1;                                 \
        }                                                                                \
        if (brow_ok) {                                                                   \
            *(uint4*)&Bs[B][srow][shalf * 16 + 0] = bu0;                                 \
            *(uint4*)&Bs[B][srow][shalf * 16 + 8] = bu1;                                 \
        }                                                                                \
        if (WIDEN && t < 16) {                                                           \
            *(uint4*)&Bs[B][EBASE + (t >> 1)][(t & 1) * 16 + 0] = eu0;                   \
            *(uint4*)&Bs[B][EBASE + (t >> 1)][(t & 1) * 16 + 8] = eu1;                   \
        }                                                                                \
    }

    G_LOAD(0);
    L_STORE(0);
    __syncthreads();
    for (int s = 0; s < nsteps; ++s) {
        const int cur = s & 1;
        if (s + 1 < nsteps) G_LOAD((s + 1) * 32);
        bf16x8 af[WRF], bfr[WCF], ef;
        #pragma unroll
        for (int f = 0; f < WRF; ++f)
            af[f] = *(const bf16x8*)&As[cur][wrow + f * 16 + lr][lq * 8];
        #pragma unroll
        for (int g = 0; g < WCF; ++g)
            bfr[g] = *(const bf16x8*)&Bs[cur][wcol + g * 16 + lr][lq * 8];
        if (xw) ef = *(const bf16x8*)&Bs[cur][EBASE + lr][lq * 8];
        #pragma unroll
        for (int f = 0; f < WRF; ++f)
            #pragma unroll
            for (int g = 0; g < WCF; ++g)
                acc[f][g] = __builtin_amdgcn_mfma_f32_16x16x32_bf16(af[f], bfr[g],
                                                                    acc[f][g], 0, 0, 0);
        if (xw) {
            #pragma unroll
            for (int f = 0; f < WRF; ++f)
                acc4[f] = __builtin_amdgcn_mfma_f32_16x16x32_bf16(af[f], ef,
                                                                  acc4[f], 0, 0, 0);
        }
        if (s + 1 < nsteps) L_STORE(cur ^ 1);
        __syncthreads();
    }
#undef G_LOAD
#undef L_STORE

    // ---- epilogue: C write (+ el/er for !WIDEN via cols M, M+1) ----
    #pragma unroll
    for (int f = 0; f < WRF; ++f) {
        #pragma unroll
        for (int g = 0; g < WCF; ++g) {
            int col = wcol + g * 16 + lr;
            #pragma unroll
            for (int r = 0; r < 4; ++r) {
                int row = r0 + wrow + f * 16 + lq * 4 + r;
                if (row >= N) continue;
                if (WIDEN || col < M) {
                    if constexpr (OBF)
                        ((unsigned short*)Y)[(size_t)row * M + col] = f2bf(acc[f][g][r]);
                    else
                        ((float*)Y)[(size_t)row * M + col] = acc[f][g][r];
                } else if (col == M) {
                    el[row] = acc[f][g][r];
                } else if (col == M + 1) {
                    er[row] = acc[f][g][r];
                }
            }
        }
    }
    if constexpr (WIDEN) {
        if (xw && lr < 8) {
            #pragma unroll
            for (int f = 0; f < WRF; ++f) {
                #pragma unroll
                for (int r = 0; r < 4; ++r) {
                    int row = r0 + wrow + f * 16 + lq * 4 + r;
                    if (row < N) {
                        float v = acc4[f][r];
                        if (lr < 4) el[(size_t)row * 4 + lr] = v;
                        else        er[(size_t)row * 4 + (lr - 4)] = v;
                    }
                }
            }
        }
    }
}

// ---------------- aggregation: wave/dst, no max (shift-invariant) ----------------

template <int H, int D, bool ELU, bool BFW, bool OB>
__global__ __launch_bounds__(256) void agg_kernel(const void* __restrict__ hsrcv,
                                                  const float* __restrict__ el,
                                                  const float* __restrict__ er,
                                                  const float* __restrict__ bias,
                                                  const int2* __restrict__ rowbe,
                                                  const int* __restrict__ csrc,
                                                  void* __restrict__ outv, int N) {
    constexpr int HD = H * D;
    int wid = (int)(((size_t)blockIdx.x * blockDim.x + threadIdx.x) >> 6);
    int lane = threadIdx.x & 63;
    if (wid >= N) return;
    int eb = BFW ? lane * 2 : lane;
    bool active = BFW || (lane < HD);
    int head = active ? (eb / D) : 0;
    float er_d = er[(size_t)wid * H + head];
    int2 be = rowbe[wid];
    int beg = be.x, end = be.y;
    const unsigned int* hb = (const unsigned int*)hsrcv;
    const float* hf = (const float*)hsrcv;

    float denom = 0.f, a0 = 0.f, a1 = 0.f;

#define AGG_UPDATE(EV, HX, HY)                                                 \
    {                                                                          \
        float e_ = (EV) + er_d;                                                \
        e_ = (e_ > 0.f) ? e_ : 0.2f * e_;                                      \
        float ex_ = __expf(e_);                                                \
        denom += ex_;                                                          \
        a0 = fmaf(ex_, (HX), a0);                                              \
        a1 = fmaf(ex_, (HY), a1);                                              \
    }

    for (int chunk = beg; chunk < end; chunk += 64) {
        int cnt = min(64, end - chunk);
        int cs = (lane < cnt) ? csrc[chunk + lane] : 0;
        int j = 0;
        for (; j + 4 <= cnt; j += 4) {
            int s0 = __shfl(cs, j + 0), s1 = __shfl(cs, j + 1);
            int s2 = __shfl(cs, j + 2), s3 = __shfl(cs, j + 3);
            float e0 = el[(size_t)s0 * H + head];
            float e1 = el[(size_t)s1 * H + head];
            float e2 = el[(size_t)s2 * H + head];
            float e3 = el[(size_t)s3 * H + head];
            float h0x, h0y = 0.f, h1x, h1y = 0.f, h2x, h2y = 0.f, h3x, h3y = 0.f;
            if (BFW) {
                unsigned int v0 = hb[(size_t)s0 * (HD / 2) + lane];
                unsigned int v1 = hb[(size_t)s1 * (HD / 2) + lane];
                unsigned int v2 = hb[(size_t)s2 * (HD / 2) + lane];
                unsigned int v3 = hb[(size_t)s3 * (HD / 2) + lane];
                h0x = bflo(v0); h0y = bfhi(v0);
                h1x = bflo(v1); h1y = bfhi(v1);
                h2x = bflo(v2); h2y = bfhi(v2);
                h3x = bflo(v3); h3y = bfhi(v3);
            } else {
                h0x = active ? hf[(size_t)s0 * HD + eb] : 0.f;
                h1x = active ? hf[(size_t)s1 * HD + eb] : 0.f;
                h2x = active ? hf[(size_t)s2 * HD + eb] : 0.f;
                h3x = active ? hf[(size_t)s3 * HD + eb] : 0.f;
            }
            AGG_UPDATE(e0, h0x, h0y);
            AGG_UPDATE(e1, h1x, h1y);
            AGG_UPDATE(e2, h2x, h2y);
            AGG_UPDATE(e3, h3x, h3y);
        }
        for (; j < cnt; ++j) {
            int s0 = __shfl(cs, j);
            float e0 = el[(size_t)s0 * H + head];
            float hx, hy = 0.f;
            if (BFW) {
                unsigned int v0 = hb[(size_t)s0 * (HD / 2) + lane];
                hx = bflo(v0); hy = bfhi(v0);
            } else {
                hx = active ? hf[(size_t)s0 * HD + eb] : 0.f;
            }
            AGG_UPDATE(e0, hx, hy);
        }
    }
#undef AGG_UPDATE

    float inv = 1.f / (denom + 1e-9f);
    if (BFW) {
        float o0 = a0 * inv + bias[eb];
        float o1 = a1 * inv + bias[eb + 1];
        if (ELU) {
            o0 = (o0 > 0.f) ? o0 : expm1f(o0);
            o1 = (o1 > 0.f) ? o1 : expm1f(o1);
        }
        if constexpr (OB) {
            ((unsigned int*)outv)[(size_t)wid * (HD / 2) + lane] = pack2bf(o0, o1);
        } else {
            *(float2*)((float*)outv + (size_t)wid * HD + eb) = make_float2(o0, o1);
        }
    } else if (active) {
        float o = a0 * inv + bias[eb];
        if (ELU) o = (o > 0.f) ? o : expm1f(o);
        ((float*)outv)[(size_t)wid * HD + eb] = o;
    }
}

// ---------------- launch ----------------

extern "C" void kernel_launch(void* const* d_in, const int* in_sizes, int n_in,
                              void* d_out, int out_size, void* d_ws, size_t ws_size,
                              hipStream_t stream) {
    const float* x    = (const float*)d_in[0];
    const int* esrc   = (const int*)d_in[1];
    const int* edst   = (const int*)d_in[2];
    const float* W1   = (const float*)d_in[3];
    const float* al1  = (const float*)d_in[4];
    const float* ar1  = (const float*)d_in[5];
    const float* b1   = (const float*)d_in[6];
    const float* W2   = (const float*)d_in[7];
    const float* al2  = (const float*)d_in[8];
    const float* ar2  = (const float*)d_in[9];
    const float* b2   = (const float*)d_in[10];
    const float* W3   = (const float*)d_in[11];
    const float* al3  = (const float*)d_in[12];
    const float* ar3  = (const float*)d_in[13];
    const float* b3   = (const float*)d_in[14];

    const int FIN = 256;
    const int N = in_sizes[0] / FIN;    // 100000
    const int E = in_sizes[1];          // 1600000
    const int D1 = HEADS * HID;         // 128
    const int NBUCK = (N + 255) >> BSH; // 391
    const int NBUCKP = 392;             // padded for 16B alignment of what follows

    unsigned short* Abf = (unsigned short*)d_ws;              // N*128 bf16
    unsigned short* Cbf = Abf + (size_t)N * D1;               // N*128 bf16
    float* A32 = (float*)(Cbf + (size_t)N * D1);              // N*40 fp32
    float* el  = A32 + (size_t)N * NCLS;                      // N*4
    float* er  = el + (size_t)N * HEADS;                      // N*4
    int2* rowbe = (int2*)(er + (size_t)N * HEADS);            // N int2
    int* csrc   = (int*)(rowbe + N);                          // NBUCK*BCAP
    int* bcur   = csrc + (size_t)NBUCK * BCAP;                // NBUCKP
    unsigned short* Wt1 = (unsigned short*)(bcur + NBUCKP);   // 128*256
    unsigned short* Wt2 = Wt1 + 128 * 256;                    // 128*128
    unsigned short* Wt3 = Wt2 + 128 * 128;                    // 40*128
    unsigned short* aw1 = Wt3 + 40 * 128;                     // 8*256
    unsigned short* aw2 = aw1 + 8 * 256;                      // 8*128
    unsigned short* aw3 = aw2 + 8 * 128;                      // 2*128
    unsigned long long* ebuf = (unsigned long long*)Abf;      // NBUCK*BCAP*8 = 19.2MB

    int WGRID = (int)(((size_t)N * 64 + 255) / 256);
    int PB = (E + CH - 1) / CH;
    int GB = (N + 127) / 128;

    // ---- fused prep ----
    prep_all<<<(57600 + NBUCK + 255) / 256, 256, 0, stream>>>(
        W1, W2, W3, al1, ar1, al2, ar2, al3, ar3,
        Wt1, Wt2, Wt3, aw1, aw2, aw3, NBUCK, bcur);

    // ---- CSR build (fixed-capacity buckets) ----
    bucket_partition<<<PB, 256, 0, stream>>>(esrc, edst, E, NBUCK, bcur, ebuf);
    bucket_csr<<<NBUCK, 256, 0, stream>>>(ebuf, bcur, N, rowbe, csrc);

    // ---- layer 1 ----
    gemm_mfma<true, true, true><<<GB, 256, 0, stream>>>(x, Wt1, aw1, Abf, el, er, N, FIN, D1);
    agg_kernel<HEADS, HID, true, true, true><<<WGRID, 256, 0, stream>>>(Abf, el, er, b1, rowbe, csrc, Cbf, N);

    // ---- layer 2 ----
    gemm_mfma<false, true, true><<<GB, 256, 0, stream>>>(Cbf, Wt2, aw2, Abf, el, er, N, D1, D1);
    agg_kernel<HEADS, HID, true, true, true><<<WGRID, 256, 0, stream>>>(Abf, el, er, b2, rowbe, csrc, Cbf, N);

    // ---- layer 3 ----
    gemm_mfma<false, false, false><<<GB, 256, 0, stream>>>(Cbf, Wt3, aw3, A32, el, er, N, D1, NCLS);
    agg_kernel<1, NCLS, false, false, false><<<WGRID, 256, 0, stream>>>(A32, el, er, b3, rowbe, csrc, d_out, N);
}